// Round 1
// baseline (935.494 us; speedup 1.0000x reference)
//
#include <hip/hip_runtime.h>

typedef _Float16 half8 __attribute__((ext_vector_type(8)));
typedef float floatx4 __attribute__((ext_vector_type(4)));

#define N_NODES 10000
#define N_EDGES 320000
#define NODE_DIM 24
#define HID 64
#define KSPLIT 192          // [hi|hi|lo] x 64  (A) vs [hi|lo|hi] x 64 (B)
#define NPAD 10112          // 79 * 128
#define NT 625              // 16-col tiles over 10000 cols
#define NSEG 16             // pass-1 column segments
#define TPS 40              // ceil(625/16) col-tiles per segment
#define CSEG 25             // pass-2 col-tiles per block (625 = 25*25)

// ---------------- K1: h0 = x @ W_in + b_in ----------------
__global__ __launch_bounds__(256) void k_node_embed(
    const float* __restrict__ x, const float* __restrict__ Win,
    const float* __restrict__ bin, float* __restrict__ h0) {
  int t = blockIdx.x * blockDim.x + threadIdx.x;
  int n = t >> 6, j = t & 63;
  if (n >= N_NODES) return;
  float acc = bin[j];
  const float* xr = x + n * NODE_DIM;
#pragma unroll
  for (int k = 0; k < NODE_DIM; ++k) acc = fmaf(xr[k], Win[k * HID + j], acc);
  h0[n * HID + j] = acc;
}

// ---------------- K2: CSR build ----------------
__global__ __launch_bounds__(256) void k_hist(const int* __restrict__ dst, int* __restrict__ cnt) {
  int e = blockIdx.x * blockDim.x + threadIdx.x;
  if (e < N_EDGES) atomicAdd(&cnt[dst[e]], 1);
}

__global__ __launch_bounds__(1024) void k_scan(const int* __restrict__ cnt,
                                               int* __restrict__ offs, int* __restrict__ cur) {
  __shared__ int part[1024];
  int tid = threadIdx.x;
  const int PER = 10;  // 1024*10 >= 10000
  int base = tid * PER;
  int loc[PER];
  int s = 0;
#pragma unroll
  for (int i = 0; i < PER; ++i) {
    int e = base + i;
    int v = (e < N_NODES) ? cnt[e] : 0;
    loc[i] = s; s += v;
  }
  part[tid] = s;
  __syncthreads();
  for (int off = 1; off < 1024; off <<= 1) {
    int v = (tid >= off) ? part[tid - off] : 0;
    __syncthreads();
    part[tid] += v;
    __syncthreads();
  }
  int pre = (tid > 0) ? part[tid - 1] : 0;
#pragma unroll
  for (int i = 0; i < PER; ++i) {
    int e = base + i;
    if (e < N_NODES) { int o = pre + loc[i]; offs[e] = o; cur[e] = o; }
  }
  if (tid == 1023) offs[N_NODES] = pre + s;
}

__global__ __launch_bounds__(256) void k_scatter(const int* __restrict__ dst,
                                                 int* __restrict__ cur, int* __restrict__ csr) {
  int e = blockIdx.x * blockDim.x + threadIdx.x;
  if (e < N_EDGES) { int p = atomicAdd(&cur[dst[e]], 1); csr[p] = e; }
}

// ---------------- K3: pull aggregation: agg[n] = sum relu(h[src]+ea) ----------------
__global__ __launch_bounds__(256) void k_agg(
    const float* __restrict__ h, const float* __restrict__ eattr,
    const int* __restrict__ src, const int* __restrict__ csr, const int* __restrict__ offs,
    const float* __restrict__ We, const float* __restrict__ be, float* __restrict__ agg) {
  int t = blockIdx.x * blockDim.x + threadIdx.x;
  int n = t >> 6, j = t & 63;
  if (n >= N_NODES) return;
  float w0 = We[j], w1 = We[HID + j], b = be[j];
  float acc = 0.f;
  int e0 = offs[n], e1 = offs[n + 1];
  for (int i = e0; i < e1; ++i) {
    int eid = csr[i];
    int sidx = src[eid];
    float a0 = eattr[2 * eid], a1 = eattr[2 * eid + 1];
    float v = h[sidx * HID + j] + fmaf(a0, w0, fmaf(a1, w1, b));
    acc += fmaxf(v, 0.f);
  }
  agg[n * HID + j] = acc;
}

// ---------------- K4: mlp(h+agg), shared weights; optional output relu ----------------
__global__ __launch_bounds__(256) void k_mlp(
    const float* __restrict__ h, const float* __restrict__ agg,
    const float* __restrict__ W1, const float* __restrict__ b1,
    const float* __restrict__ W2, const float* __restrict__ b2,
    float* __restrict__ hout, int dorelu) {
  __shared__ float zs[4][HID];
  __shared__ float ts[4][HID];
  int t = blockIdx.x * blockDim.x + threadIdx.x;
  int n = t >> 6, j = t & 63, nl = threadIdx.x >> 6;
  float z = h[n * HID + j] + agg[n * HID + j];
  zs[nl][j] = z;
  __syncthreads();
  float acc = b1[j];
#pragma unroll 16
  for (int k = 0; k < HID; ++k) acc = fmaf(zs[nl][k], W1[k * HID + j], acc);
  float tv = fmaxf(acc, 0.f);
  ts[nl][j] = tv;
  __syncthreads();
  float acc2 = b2[j];
#pragma unroll 16
  for (int k = 0; k < HID; ++k) acc2 = fmaf(ts[nl][k], W2[k * HID + j], acc2);
  hout[n * HID + j] = dorelu ? fmaxf(acc2, 0.f) : acc2;
}

// ------- K5: layer-2 mlp -> h2, hM = h2@M; emit split-f16 operand layouts -------
__global__ __launch_bounds__(256) void k_mlp2_prep(
    const float* __restrict__ h, const float* __restrict__ agg,
    const float* __restrict__ W1, const float* __restrict__ b1,
    const float* __restrict__ W2, const float* __restrict__ b2,
    const float* __restrict__ Mw, _Float16* __restrict__ Ap, _Float16* __restrict__ Bp) {
  __shared__ float zs[4][HID];
  __shared__ float ts[4][HID];
  __shared__ float hs[4][HID];
  int t = blockIdx.x * blockDim.x + threadIdx.x;
  int n = t >> 6, j = t & 63, nl = threadIdx.x >> 6;
  float z = h[n * HID + j] + agg[n * HID + j];
  zs[nl][j] = z;
  __syncthreads();
  float acc = b1[j];
#pragma unroll 16
  for (int k = 0; k < HID; ++k) acc = fmaf(zs[nl][k], W1[k * HID + j], acc);
  float tv = fmaxf(acc, 0.f);
  ts[nl][j] = tv;
  __syncthreads();
  float acc2 = b2[j];
#pragma unroll 16
  for (int k = 0; k < HID; ++k) acc2 = fmaf(ts[nl][k], W2[k * HID + j], acc2);
  // h2 (no relu)
  hs[nl][j] = acc2;
  _Float16 bhi = (_Float16)acc2;
  _Float16 blo = (_Float16)(acc2 - (float)bhi);
  _Float16* brow = Bp + (size_t)n * KSPLIT;
  brow[j] = bhi; brow[64 + j] = blo; brow[128 + j] = bhi;
  __syncthreads();
  float accm = 0.f;
#pragma unroll 16
  for (int k = 0; k < HID; ++k) accm = fmaf(hs[nl][k], Mw[k * HID + j], accm);
  _Float16 ahi = (_Float16)accm;
  _Float16 alo = (_Float16)(accm - (float)ahi);
  _Float16* arow = Ap + (size_t)n * KSPLIT;
  arow[j] = ahi; arow[64 + j] = ahi; arow[128 + j] = alo;
}

// ---------------- K6: pass 1 — row max + sum-exp (online, wave-voted skip) ----------------
__global__ __launch_bounds__(256) void k_pass1(
    const _Float16* __restrict__ Ap, const _Float16* __restrict__ Bp,
    float* __restrict__ pm, float* __restrict__ ps) {
  int seg = blockIdx.x & 15;
  int rg = blockIdx.x >> 4;
  int wave = threadIdx.x >> 6, lane = threadIdx.x & 63;
  int quad = lane >> 4, l16 = lane & 15;
  int rowbase = rg * 128 + wave * 32;
  const half8* A = (const half8*)Ap;  // row stride = 24 half8
  const half8* B = (const half8*)Bp;
  half8 af[2][6];
#pragma unroll
  for (int tt = 0; tt < 2; ++tt) {
    int ar = rowbase + tt * 16 + l16;
#pragma unroll
    for (int s = 0; s < 6; ++s) af[tt][s] = A[ar * 24 + s * 4 + quad];
  }
  float m[8], sum[8];
#pragma unroll
  for (int i = 0; i < 8; ++i) { m[i] = -3.0e38f; sum[i] = 0.f; }
  int ct0 = seg * TPS;
  int ct1 = ct0 + TPS; if (ct1 > NT) ct1 = NT;
  for (int ct = ct0; ct < ct1; ++ct) {
    int br = ct * 16 + l16;
    half8 bf[6];
#pragma unroll
    for (int s = 0; s < 6; ++s) bf[s] = B[br * 24 + s * 4 + quad];
    floatx4 acc0 = {0.f, 0.f, 0.f, 0.f}, acc1 = {0.f, 0.f, 0.f, 0.f};
#pragma unroll
    for (int s = 0; s < 6; ++s) {
      acc0 = __builtin_amdgcn_mfma_f32_16x16x32_f16(af[0][s], bf[s], acc0, 0, 0, 0);
      acc1 = __builtin_amdgcn_mfma_f32_16x16x32_f16(af[1][s], bf[s], acc1, 0, 0, 0);
    }
    float d[8];
#pragma unroll
    for (int i = 0; i < 4; ++i) { d[i] = acc0[i]; d[4 + i] = acc1[i]; }
    bool need = false;
#pragma unroll
    for (int i = 0; i < 8; ++i) need |= (d[i] > m[i] - 20.f);
    if (__any((int)need)) {
#pragma unroll
      for (int i = 0; i < 8; ++i) {
        float nm = fmaxf(m[i], d[i]);
        sum[i] = sum[i] * __expf(m[i] - nm) + __expf(d[i] - nm);
        m[i] = nm;
      }
    }
  }
  // combine across the 16 lanes of each quad (they cover cols mod 16)
#pragma unroll
  for (int off = 1; off < 16; off <<= 1) {
#pragma unroll
    for (int i = 0; i < 8; ++i) {
      float mo = __shfl_xor(m[i], off);
      float so = __shfl_xor(sum[i], off);
      float nm = fmaxf(m[i], mo);
      sum[i] = sum[i] * __expf(m[i] - nm) + so * __expf(mo - nm);
      m[i] = nm;
    }
  }
  if (l16 == 0) {
#pragma unroll
    for (int i = 0; i < 8; ++i) {
      int row = rowbase + (i >> 2) * 16 + quad * 4 + (i & 3);
      if (row < N_NODES) {
        pm[seg * N_NODES + row] = m[i];
        ps[seg * N_NODES + row] = sum[i];
      }
    }
  }
}

// ---------------- K7: combine segment stats ----------------
__global__ __launch_bounds__(256) void k_combine(
    const float* __restrict__ pm, const float* __restrict__ ps,
    float* __restrict__ Mrow, float* __restrict__ iS) {
  int r = blockIdx.x * blockDim.x + threadIdx.x;
  if (r >= N_NODES) return;
  float M = -3.0e38f;
#pragma unroll
  for (int s = 0; s < NSEG; ++s) M = fmaxf(M, pm[s * N_NODES + r]);
  float S = 0.f;
#pragma unroll
  for (int s = 0; s < NSEG; ++s) S += ps[s * N_NODES + r] * __expf(pm[s * N_NODES + r] - M);
  Mrow[r] = M;
  iS[r] = 1.f / S;
}

// ---------------- K8: pass 2 — recompute logits, write softmax ----------------
__global__ __launch_bounds__(256) void k_pass2(
    const _Float16* __restrict__ Ap, const _Float16* __restrict__ Bp,
    const float* __restrict__ Mrow, const float* __restrict__ iS, float* __restrict__ out) {
  int cs = blockIdx.x % CSEG;
  int rg = blockIdx.x / CSEG;
  int wave = threadIdx.x >> 6, lane = threadIdx.x & 63;
  int quad = lane >> 4, l16 = lane & 15;
  int rowbase = rg * 128 + wave * 32;
  const half8* A = (const half8*)Ap;
  const half8* B = (const half8*)Bp;
  half8 af[2][6];
#pragma unroll
  for (int tt = 0; tt < 2; ++tt) {
    int ar = rowbase + tt * 16 + l16;
#pragma unroll
    for (int s = 0; s < 6; ++s) af[tt][s] = A[ar * 24 + s * 4 + quad];
  }
  float Mv[8], Iv[8];
  int rowv[8];
#pragma unroll
  for (int i = 0; i < 8; ++i) {
    int row = rowbase + (i >> 2) * 16 + quad * 4 + (i & 3);
    rowv[i] = row;
    Mv[i] = (row < N_NODES) ? Mrow[row] : 0.f;
    Iv[i] = (row < N_NODES) ? iS[row] : 0.f;
  }
  for (int ct = cs * CSEG; ct < cs * CSEG + CSEG; ++ct) {
    int br = ct * 16 + l16;
    half8 bf[6];
#pragma unroll
    for (int s = 0; s < 6; ++s) bf[s] = B[br * 24 + s * 4 + quad];
    floatx4 acc0 = {0.f, 0.f, 0.f, 0.f}, acc1 = {0.f, 0.f, 0.f, 0.f};
#pragma unroll
    for (int s = 0; s < 6; ++s) {
      acc0 = __builtin_amdgcn_mfma_f32_16x16x32_f16(af[0][s], bf[s], acc0, 0, 0, 0);
      acc1 = __builtin_amdgcn_mfma_f32_16x16x32_f16(af[1][s], bf[s], acc1, 0, 0, 0);
    }
    float d[8];
#pragma unroll
    for (int i = 0; i < 4; ++i) { d[i] = acc0[i]; d[4 + i] = acc1[i]; }
    int col = ct * 16 + l16;
#pragma unroll
    for (int i = 0; i < 8; ++i) {
      if (rowv[i] < N_NODES)
        out[(size_t)rowv[i] * N_NODES + col] = __expf(d[i] - Mv[i]) * Iv[i];
    }
  }
}

extern "C" void kernel_launch(void* const* d_in, const int* in_sizes, int n_in,
                              void* d_out, int out_size, void* d_ws, size_t ws_size,
                              hipStream_t stream) {
  const float* x     = (const float*)d_in[0];
  const float* eattr = (const float*)d_in[1];
  const int*   eidx  = (const int*)d_in[2];
  const float* Win   = (const float*)d_in[3];
  const float* bin   = (const float*)d_in[4];
  const float* We    = (const float*)d_in[5];
  const float* be    = (const float*)d_in[6];
  const float* W1    = (const float*)d_in[7];
  const float* b1    = (const float*)d_in[8];
  const float* W2    = (const float*)d_in[9];
  const float* b2    = (const float*)d_in[10];
  const float* Mw    = (const float*)d_in[11];
  float* out = (float*)d_out;
  const int* src = eidx;
  const int* dst = eidx + N_EDGES;

  char* w = (char*)d_ws;
  auto alloc = [&](size_t bytes) { char* p = w; w += (bytes + 255) & ~(size_t)255; return p; };
  float*    h0   = (float*)alloc((size_t)N_NODES * HID * 4);
  float*    agg  = (float*)alloc((size_t)N_NODES * HID * 4);
  float*    h1   = (float*)alloc((size_t)N_NODES * HID * 4);
  _Float16* Ap   = (_Float16*)alloc((size_t)NPAD * KSPLIT * 2);
  _Float16* Bp   = (_Float16*)alloc((size_t)NPAD * KSPLIT * 2);
  int*      csr  = (int*)alloc((size_t)N_EDGES * 4);
  int*      cnt  = (int*)alloc((size_t)(N_NODES + 1) * 4);
  int*      offs = (int*)alloc((size_t)(N_NODES + 1) * 4);
  int*      cur  = (int*)alloc((size_t)(N_NODES + 1) * 4);
  float*    pm   = (float*)alloc((size_t)NSEG * N_NODES * 4);
  float*    ps   = (float*)alloc((size_t)NSEG * N_NODES * 4);
  float*    Mrow = (float*)alloc((size_t)N_NODES * 4);
  float*    iS   = (float*)alloc((size_t)N_NODES * 4);

  hipMemsetAsync(cnt, 0, (N_NODES + 1) * 4, stream);
  // zero pad rows of the MFMA operand buffers (rows 10000..10111)
  hipMemsetAsync(Ap + (size_t)N_NODES * KSPLIT, 0, (size_t)(NPAD - N_NODES) * KSPLIT * 2, stream);
  hipMemsetAsync(Bp + (size_t)N_NODES * KSPLIT, 0, (size_t)(NPAD - N_NODES) * KSPLIT * 2, stream);

  k_node_embed<<<(N_NODES * HID) / 256, 256, 0, stream>>>(x, Win, bin, h0);
  k_hist<<<N_EDGES / 256, 256, 0, stream>>>(dst, cnt);
  k_scan<<<1, 1024, 0, stream>>>(cnt, offs, cur);
  k_scatter<<<N_EDGES / 256, 256, 0, stream>>>(dst, cur, csr);

  // GINE layer 1 (relu on output)
  k_agg<<<(N_NODES * HID) / 256, 256, 0, stream>>>(h0, eattr, src, csr, offs, We, be, agg);
  k_mlp<<<(N_NODES * HID) / 256, 256, 0, stream>>>(h0, agg, W1, b1, W2, b2, h1, 1);
  // GINE layer 2 (no relu) + decode prep (h2, hM, split-f16 operands)
  k_agg<<<(N_NODES * HID) / 256, 256, 0, stream>>>(h1, eattr, src, csr, offs, We, be, agg);
  k_mlp2_prep<<<(N_NODES * HID) / 256, 256, 0, stream>>>(h1, agg, W1, b1, W2, b2, Mw, Ap, Bp);

  // decode: two-pass fused softmax over 10000x10000 logits
  k_pass1<<<79 * NSEG, 256, 0, stream>>>(Ap, Bp, pm, ps);
  k_combine<<<(N_NODES + 255) / 256, 256, 0, stream>>>(pm, ps, Mrow, iS);
  k_pass2<<<79 * CSEG, 256, 0, stream>>>(Ap, Bp, Mrow, iS, out);
}

// Round 2
// 748.177 us; speedup vs baseline: 1.2504x; 1.2504x over previous
//
#include <hip/hip_runtime.h>

typedef _Float16 half8 __attribute__((ext_vector_type(8)));
typedef float floatx4 __attribute__((ext_vector_type(4)));

#define N_NODES 10000
#define N_EDGES 320000
#define NODE_DIM 24
#define HID 64
#define KSPLIT 192          // A=[hi|hi|lo] x 64, B=[hi|lo|hi] x 64
#define NPAD 10112          // 79 * 128 (A rows padded)
#define NT 625              // 16-col tiles over 10000 cols (exact)
#define NSEG 16             // pass-1 column segments
#define TPS 40              // col-tiles per segment (ceil 625/16)
#define CSEG 25             // pass-2 col-tiles per block (625 = 25*25)

// ---------------- K1: h0 = x @ W_in + b_in, fused edge histogram ----------------
__global__ __launch_bounds__(256) void k_embed_hist(
    const float* __restrict__ x, const float* __restrict__ Win,
    const float* __restrict__ bin, float* __restrict__ h0,
    const int* __restrict__ dst, int* __restrict__ cnt) {
  int t = blockIdx.x * blockDim.x + threadIdx.x;
  if (t < N_EDGES) atomicAdd(&cnt[dst[t]], 1);
  int n = t >> 6, j = t & 63;
  if (n >= N_NODES) return;
  float acc = bin[j];
  const float* xr = x + n * NODE_DIM;
#pragma unroll
  for (int k = 0; k < NODE_DIM; ++k) acc = fmaf(xr[k], Win[k * HID + j], acc);
  h0[n * HID + j] = acc;
}

// ---------------- K2: CSR build ----------------
__global__ __launch_bounds__(1024) void k_scan(const int* __restrict__ cnt,
                                               int* __restrict__ offs, int* __restrict__ cur) {
  __shared__ int part[1024];
  int tid = threadIdx.x;
  const int PER = 10;  // 1024*10 >= 10000
  int base = tid * PER;
  int loc[PER];
  int s = 0;
#pragma unroll
  for (int i = 0; i < PER; ++i) {
    int e = base + i;
    int v = (e < N_NODES) ? cnt[e] : 0;
    loc[i] = s; s += v;
  }
  part[tid] = s;
  __syncthreads();
  for (int off = 1; off < 1024; off <<= 1) {
    int v = (tid >= off) ? part[tid - off] : 0;
    __syncthreads();
    part[tid] += v;
    __syncthreads();
  }
  int pre = (tid > 0) ? part[tid - 1] : 0;
#pragma unroll
  for (int i = 0; i < PER; ++i) {
    int e = base + i;
    if (e < N_NODES) { int o = pre + loc[i]; offs[e] = o; cur[e] = o; }
  }
  if (tid == 1023) offs[N_NODES] = pre + s;
}

__global__ __launch_bounds__(256) void k_scatter(const int* __restrict__ dst,
                                                 int* __restrict__ cur, int* __restrict__ csr) {
  int e = blockIdx.x * blockDim.x + threadIdx.x;
  if (e < N_EDGES) { int p = atomicAdd(&cur[dst[e]], 1); csr[p] = e; }
}

// ---------------- K3: pull aggregation: agg[n] = sum relu(h[src]+ea) ----------------
__global__ __launch_bounds__(256) void k_agg(
    const float* __restrict__ h, const float* __restrict__ eattr,
    const int* __restrict__ src, const int* __restrict__ csr, const int* __restrict__ offs,
    const float* __restrict__ We, const float* __restrict__ be, float* __restrict__ agg) {
  int t = blockIdx.x * blockDim.x + threadIdx.x;
  int n = t >> 6, j = t & 63;
  if (n >= N_NODES) return;
  float w0 = We[j], w1 = We[HID + j], b = be[j];
  const float2* ea2 = (const float2*)eattr;
  float acc = 0.f;
  int e0 = offs[n], e1 = offs[n + 1];
  int i = e0;
  // 2x unrolled: independent load chains per iteration
  for (; i + 1 < e1; i += 2) {
    int ea_ = csr[i], eb_ = csr[i + 1];
    int sa = src[ea_], sb = src[eb_];
    float2 aa = ea2[ea_], ab = ea2[eb_];
    float va = h[sa * HID + j] + fmaf(aa.x, w0, fmaf(aa.y, w1, b));
    float vb = h[sb * HID + j] + fmaf(ab.x, w0, fmaf(ab.y, w1, b));
    acc += fmaxf(va, 0.f) + fmaxf(vb, 0.f);
  }
  if (i < e1) {
    int ea_ = csr[i];
    int sa = src[ea_];
    float2 aa = ea2[ea_];
    float va = h[sa * HID + j] + fmaf(aa.x, w0, fmaf(aa.y, w1, b));
    acc += fmaxf(va, 0.f);
  }
  agg[n * HID + j] = acc;
}

// ---------------- K4: mlp(h+agg), shared weights; optional output relu ----------------
__global__ __launch_bounds__(256) void k_mlp(
    const float* __restrict__ h, const float* __restrict__ agg,
    const float* __restrict__ W1, const float* __restrict__ b1,
    const float* __restrict__ W2, const float* __restrict__ b2,
    float* __restrict__ hout, int dorelu) {
  __shared__ float zs[4][HID];
  __shared__ float ts[4][HID];
  int t = blockIdx.x * blockDim.x + threadIdx.x;
  int n = t >> 6, j = t & 63, nl = threadIdx.x >> 6;
  float z = h[n * HID + j] + agg[n * HID + j];
  zs[nl][j] = z;
  __syncthreads();
  float acc = b1[j];
#pragma unroll 16
  for (int k = 0; k < HID; ++k) acc = fmaf(zs[nl][k], W1[k * HID + j], acc);
  float tv = fmaxf(acc, 0.f);
  ts[nl][j] = tv;
  __syncthreads();
  float acc2 = b2[j];
#pragma unroll 16
  for (int k = 0; k < HID; ++k) acc2 = fmaf(ts[nl][k], W2[k * HID + j], acc2);
  hout[n * HID + j] = dorelu ? fmaxf(acc2, 0.f) : acc2;
}

// ------- K5: layer-2 mlp -> h2, hM = h2@M; emit MFMA operand layouts -------
// A (hM rows): padded-row layout, KSPLIT halves per row  = [hi|hi|lo]
// B (h2 rows): FRAGMENT-MAJOR: half8 unit index (ct*6+s)*64 + quad*16 + l16,
//              element j inside unit; (col n, k) -> ct=n/16,l16=n%16,s=k/32,
//              quad=(k%32)/8, j=k%8.  K layout = [hi|lo|hi].
__global__ __launch_bounds__(256) void k_mlp2_prep(
    const float* __restrict__ h, const float* __restrict__ agg,
    const float* __restrict__ W1, const float* __restrict__ b1,
    const float* __restrict__ W2, const float* __restrict__ b2,
    const float* __restrict__ Mw, _Float16* __restrict__ Ap, _Float16* __restrict__ Bf) {
  __shared__ float zs[4][HID];
  __shared__ float ts[4][HID];
  __shared__ float hs[4][HID];
  int t = blockIdx.x * blockDim.x + threadIdx.x;
  int n = t >> 6, j = t & 63, nl = threadIdx.x >> 6;
  float z = h[n * HID + j] + agg[n * HID + j];
  zs[nl][j] = z;
  __syncthreads();
  float acc = b1[j];
#pragma unroll 16
  for (int k = 0; k < HID; ++k) acc = fmaf(zs[nl][k], W1[k * HID + j], acc);
  float tv = fmaxf(acc, 0.f);
  ts[nl][j] = tv;
  __syncthreads();
  float acc2 = b2[j];
#pragma unroll 16
  for (int k = 0; k < HID; ++k) acc2 = fmaf(ts[nl][k], W2[k * HID + j], acc2);
  hs[nl][j] = acc2;  // h2 (no relu)
  // B fragment-major writes: [hi | lo | hi]
  {
    _Float16 bhi = (_Float16)acc2;
    _Float16 blo = (_Float16)(acc2 - (float)bhi);
    int ct = n >> 4, l16 = n & 15;
    int kk[3] = { j, 64 + j, 128 + j };
    _Float16 vv[3] = { bhi, blo, bhi };
#pragma unroll
    for (int q = 0; q < 3; ++q) {
      int k = kk[q];
      int s = k >> 5, quad = (k & 31) >> 3, jj = k & 7;
      Bf[((((ct * 6 + s) * 64) + quad * 16 + l16) << 3) + jj] = vv[q];
    }
  }
  __syncthreads();
  float accm = 0.f;
#pragma unroll 16
  for (int k = 0; k < HID; ++k) accm = fmaf(hs[nl][k], Mw[k * HID + j], accm);
  _Float16 ahi = (_Float16)accm;
  _Float16 alo = (_Float16)(accm - (float)ahi);
  _Float16* arow = Ap + (size_t)n * KSPLIT;
  arow[j] = ahi; arow[64 + j] = ahi; arow[128 + j] = alo;
}

// ---------------- K6: pass 1 — row max + sum-exp (online, wave-voted skip) ----------------
__global__ __launch_bounds__(256) void k_pass1(
    const _Float16* __restrict__ Ap, const _Float16* __restrict__ Bfh,
    float* __restrict__ pm, float* __restrict__ ps) {
  int seg = blockIdx.x & 15;
  int rg = blockIdx.x >> 4;
  int wave = threadIdx.x >> 6, lane = threadIdx.x & 63;
  int quad = lane >> 4, l16 = lane & 15;
  int rowbase = rg * 128 + wave * 32;
  const half8* A = (const half8*)Ap;   // row stride = 24 half8
  const half8* Bf = (const half8*)Bfh; // fragment-major
  half8 af[2][6];
#pragma unroll
  for (int tt = 0; tt < 2; ++tt) {
    int ar = rowbase + tt * 16 + l16;
#pragma unroll
    for (int s = 0; s < 6; ++s) af[tt][s] = A[ar * 24 + s * 4 + quad];
  }
  float m[8], sum[8];
#pragma unroll
  for (int i = 0; i < 8; ++i) { m[i] = -3.0e38f; sum[i] = 0.f; }
  int ct0 = seg * TPS;
  int ct1 = ct0 + TPS; if (ct1 > NT) ct1 = NT;
  for (int ct = ct0; ct < ct1; ++ct) {
    half8 bf[6];
#pragma unroll
    for (int s = 0; s < 6; ++s) bf[s] = Bf[(ct * 6 + s) * 64 + lane];  // coalesced 1KB
    floatx4 acc0 = {0.f, 0.f, 0.f, 0.f}, acc1 = {0.f, 0.f, 0.f, 0.f};
#pragma unroll
    for (int s = 0; s < 6; ++s) {
      acc0 = __builtin_amdgcn_mfma_f32_16x16x32_f16(af[0][s], bf[s], acc0, 0, 0, 0);
      acc1 = __builtin_amdgcn_mfma_f32_16x16x32_f16(af[1][s], bf[s], acc1, 0, 0, 0);
    }
    float d[8];
#pragma unroll
    for (int i = 0; i < 4; ++i) { d[i] = acc0[i]; d[4 + i] = acc1[i]; }
    bool need = false;
#pragma unroll
    for (int i = 0; i < 8; ++i) need |= (d[i] > m[i] - 20.f);
    if (__any((int)need)) {
#pragma unroll
      for (int i = 0; i < 8; ++i) {
        float nm = fmaxf(m[i], d[i]);
        sum[i] = sum[i] * __expf(m[i] - nm) + __expf(d[i] - nm);
        m[i] = nm;
      }
    }
  }
  // combine across the 16 l16 lanes (cols mod 16)
#pragma unroll
  for (int off = 1; off < 16; off <<= 1) {
#pragma unroll
    for (int i = 0; i < 8; ++i) {
      float mo = __shfl_xor(m[i], off);
      float so = __shfl_xor(sum[i], off);
      float nm = fmaxf(m[i], mo);
      sum[i] = sum[i] * __expf(m[i] - nm) + so * __expf(mo - nm);
      m[i] = nm;
    }
  }
  if (l16 == 0) {
#pragma unroll
    for (int i = 0; i < 8; ++i) {
      int row = rowbase + (i >> 2) * 16 + quad * 4 + (i & 3);
      if (row < N_NODES) {
        pm[seg * N_NODES + row] = m[i];
        ps[seg * N_NODES + row] = sum[i];
      }
    }
  }
}

// ---------------- K7: combine segment stats ----------------
__global__ __launch_bounds__(256) void k_combine(
    const float* __restrict__ pm, const float* __restrict__ ps,
    float* __restrict__ Mrow, float* __restrict__ iS) {
  int r = blockIdx.x * blockDim.x + threadIdx.x;
  if (r >= N_NODES) return;
  float M = -3.0e38f;
#pragma unroll
  for (int s = 0; s < NSEG; ++s) M = fmaxf(M, pm[s * N_NODES + r]);
  float S = 0.f;
#pragma unroll
  for (int s = 0; s < NSEG; ++s) S += ps[s * N_NODES + r] * __expf(pm[s * N_NODES + r] - M);
  Mrow[r] = M;
  iS[r] = 1.f / S;
}

// ---------------- K8: pass 2 — recompute logits, write softmax (nontemporal) ----------------
__global__ __launch_bounds__(256) void k_pass2(
    const _Float16* __restrict__ Ap, const _Float16* __restrict__ Bfh,
    const float* __restrict__ Mrow, const float* __restrict__ iS, float* __restrict__ out) {
  int cs = blockIdx.x % CSEG;
  int rg = blockIdx.x / CSEG;
  int wave = threadIdx.x >> 6, lane = threadIdx.x & 63;
  int quad = lane >> 4, l16 = lane & 15;
  int rowbase = rg * 128 + wave * 32;
  const half8* A = (const half8*)Ap;
  const half8* Bf = (const half8*)Bfh;
  half8 af[2][6];
#pragma unroll
  for (int tt = 0; tt < 2; ++tt) {
    int ar = rowbase + tt * 16 + l16;
#pragma unroll
    for (int s = 0; s < 6; ++s) af[tt][s] = A[ar * 24 + s * 4 + quad];
  }
  float Mv[8], Iv[8];
  int rowv[8];
#pragma unroll
  for (int i = 0; i < 8; ++i) {
    int row = rowbase + (i >> 2) * 16 + quad * 4 + (i & 3);
    rowv[i] = row;
    Mv[i] = (row < N_NODES) ? Mrow[row] : 0.f;
    Iv[i] = (row < N_NODES) ? iS[row] : 0.f;
  }
  for (int ct = cs * CSEG; ct < cs * CSEG + CSEG; ++ct) {
    half8 bf[6];
#pragma unroll
    for (int s = 0; s < 6; ++s) bf[s] = Bf[(ct * 6 + s) * 64 + lane];  // coalesced 1KB
    floatx4 acc0 = {0.f, 0.f, 0.f, 0.f}, acc1 = {0.f, 0.f, 0.f, 0.f};
#pragma unroll
    for (int s = 0; s < 6; ++s) {
      acc0 = __builtin_amdgcn_mfma_f32_16x16x32_f16(af[0][s], bf[s], acc0, 0, 0, 0);
      acc1 = __builtin_amdgcn_mfma_f32_16x16x32_f16(af[1][s], bf[s], acc1, 0, 0, 0);
    }
    float d[8];
#pragma unroll
    for (int i = 0; i < 4; ++i) { d[i] = acc0[i]; d[4 + i] = acc1[i]; }
    int col = ct * 16 + l16;
#pragma unroll
    for (int i = 0; i < 8; ++i) {
      if (rowv[i] < N_NODES) {
        float v = __expf(d[i] - Mv[i]) * Iv[i];
        __builtin_nontemporal_store(v, &out[(size_t)rowv[i] * N_NODES + col]);
      }
    }
  }
}

extern "C" void kernel_launch(void* const* d_in, const int* in_sizes, int n_in,
                              void* d_out, int out_size, void* d_ws, size_t ws_size,
                              hipStream_t stream) {
  const float* x     = (const float*)d_in[0];
  const float* eattr = (const float*)d_in[1];
  const int*   eidx  = (const int*)d_in[2];
  const float* Win   = (const float*)d_in[3];
  const float* bin   = (const float*)d_in[4];
  const float* We    = (const float*)d_in[5];
  const float* be    = (const float*)d_in[6];
  const float* W1    = (const float*)d_in[7];
  const float* b1    = (const float*)d_in[8];
  const float* W2    = (const float*)d_in[9];
  const float* b2    = (const float*)d_in[10];
  const float* Mw    = (const float*)d_in[11];
  float* out = (float*)d_out;
  const int* src = eidx;
  const int* dst = eidx + N_EDGES;

  char* w = (char*)d_ws;
  auto alloc = [&](size_t bytes) { char* p = w; w += (bytes + 255) & ~(size_t)255; return p; };
  float*    h0   = (float*)alloc((size_t)N_NODES * HID * 4);
  float*    agg  = (float*)alloc((size_t)N_NODES * HID * 4);
  float*    h1   = (float*)alloc((size_t)N_NODES * HID * 4);
  _Float16* Ap   = (_Float16*)alloc((size_t)NPAD * KSPLIT * 2);
  _Float16* Bf   = (_Float16*)alloc((size_t)NT * 6 * 64 * 8 * 2);  // 3.84 MB fragment-major
  int*      csr  = (int*)alloc((size_t)N_EDGES * 4);
  int*      cnt  = (int*)alloc((size_t)(N_NODES + 1) * 4);
  int*      offs = (int*)alloc((size_t)(N_NODES + 1) * 4);
  int*      cur  = (int*)alloc((size_t)(N_NODES + 1) * 4);
  float*    pm   = (float*)alloc((size_t)NSEG * N_NODES * 4);
  float*    ps   = (float*)alloc((size_t)NSEG * N_NODES * 4);
  float*    Mrow = (float*)alloc((size_t)N_NODES * 4);
  float*    iS   = (float*)alloc((size_t)N_NODES * 4);

  hipMemsetAsync(cnt, 0, (N_NODES + 1) * 4, stream);
  // zero A pad rows (10000..10111); B needs no pad (10000 % 16 == 0)
  hipMemsetAsync(Ap + (size_t)N_NODES * KSPLIT, 0, (size_t)(NPAD - N_NODES) * KSPLIT * 2, stream);

  k_embed_hist<<<(N_NODES * HID) / 256, 256, 0, stream>>>(x, Win, bin, h0, dst, cnt);
  k_scan<<<1, 1024, 0, stream>>>(cnt, offs, cur);
  k_scatter<<<N_EDGES / 256, 256, 0, stream>>>(dst, cur, csr);

  // GINE layer 1 (relu on output)
  k_agg<<<(N_NODES * HID) / 256, 256, 0, stream>>>(h0, eattr, src, csr, offs, We, be, agg);
  k_mlp<<<(N_NODES * HID) / 256, 256, 0, stream>>>(h0, agg, W1, b1, W2, b2, h1, 1);
  // GINE layer 2 (no relu) + decode prep (h2, hM, MFMA operand layouts)
  k_agg<<<(N_NODES * HID) / 256, 256, 0, stream>>>(h1, eattr, src, csr, offs, We, be, agg);
  k_mlp2_prep<<<(N_NODES * HID) / 256, 256, 0, stream>>>(h1, agg, W1, b1, W2, b2, Mw, Ap, Bf);

  // decode: two-pass fused softmax over 10000x10000 logits
  k_pass1<<<79 * NSEG, 256, 0, stream>>>(Ap, Bf, pm, ps);
  k_combine<<<(N_NODES + 255) / 256, 256, 0, stream>>>(pm, ps, Mrow, iS);
  k_pass2<<<79 * CSEG, 256, 0, stream>>>(Ap, Bf, Mrow, iS, out);
}

// Round 3
// 720.936 us; speedup vs baseline: 1.2976x; 1.0378x over previous
//
#include <hip/hip_runtime.h>

typedef _Float16 half8 __attribute__((ext_vector_type(8)));
typedef float floatx4 __attribute__((ext_vector_type(4)));

#define N_NODES 10000
#define N_EDGES 320000
#define NODE_DIM 24
#define HID 64
#define KSPLIT 192          // A=[hi|hi|lo] x 64, B=[hi|lo|hi] x 64
#define NPAD 10112          // 79 * 128 (A rows padded)
#define NT 625              // 16-col tiles over 10000 cols (exact)
#define NSEG 16             // pass-1 column segments
#define TPS 40              // col-tiles per segment (ceil 625/16)
#define CSEG 25             // pass-2 col-tiles per block (625 = 25*25)

// ---------------- K1: h0 = x @ W_in + b_in, fused edge histogram ----------------
__global__ __launch_bounds__(256) void k_embed_hist(
    const float* __restrict__ x, const float* __restrict__ Win,
    const float* __restrict__ bin, float* __restrict__ h0,
    const int* __restrict__ dst, int* __restrict__ cnt) {
  int t = blockIdx.x * blockDim.x + threadIdx.x;
  if (t < N_EDGES) atomicAdd(&cnt[dst[t]], 1);
  int n = t >> 6, j = t & 63;
  if (n >= N_NODES) return;
  float acc = bin[j];
  const float* xr = x + n * NODE_DIM;
#pragma unroll
  for (int k = 0; k < NODE_DIM; ++k) acc = fmaf(xr[k], Win[k * HID + j], acc);
  h0[n * HID + j] = acc;
}

// ---------------- K2: CSR offsets (single-block scan) ----------------
__global__ __launch_bounds__(1024) void k_scan(const int* __restrict__ cnt,
                                               int* __restrict__ offs, int* __restrict__ cur) {
  __shared__ int part[1024];
  int tid = threadIdx.x;
  const int PER = 10;  // 1024*10 >= 10000
  int base = tid * PER;
  int loc[PER];
  int s = 0;
#pragma unroll
  for (int i = 0; i < PER; ++i) {
    int e = base + i;
    int v = (e < N_NODES) ? cnt[e] : 0;
    loc[i] = s; s += v;
  }
  part[tid] = s;
  __syncthreads();
  for (int off = 1; off < 1024; off <<= 1) {
    int v = (tid >= off) ? part[tid - off] : 0;
    __syncthreads();
    part[tid] += v;
    __syncthreads();
  }
  int pre = (tid > 0) ? part[tid - 1] : 0;
#pragma unroll
  for (int i = 0; i < PER; ++i) {
    int e = base + i;
    if (e < N_NODES) { int o = pre + loc[i]; offs[e] = o; cur[e] = o; }
  }
  if (tid == 1023) offs[N_NODES] = pre + s;
}

__global__ __launch_bounds__(256) void k_scatter(const int* __restrict__ dst,
                                                 int* __restrict__ cur, int* __restrict__ csr) {
  int e = blockIdx.x * blockDim.x + threadIdx.x;
  if (e < N_EDGES) { int p = atomicAdd(&cur[dst[e]], 1); csr[p] = e; }
}

// ---------------- K3: fused GINE layer 1: h1 = relu(mlp(h0 + agg)) ----------------
__global__ __launch_bounds__(256) void k_gine1(
    const float* __restrict__ h, const float* __restrict__ eattr,
    const int* __restrict__ src, const int* __restrict__ csr, const int* __restrict__ offs,
    const float* __restrict__ We, const float* __restrict__ be,
    const float* __restrict__ W1, const float* __restrict__ b1,
    const float* __restrict__ W2, const float* __restrict__ b2,
    float* __restrict__ hout) {
  __shared__ float zs[4][HID];
  __shared__ float ts[4][HID];
  int t = blockIdx.x * blockDim.x + threadIdx.x;
  int n = t >> 6, j = t & 63, nl = threadIdx.x >> 6;
  float w0 = We[j], w1 = We[HID + j], b = be[j];
  const float2* ea2 = (const float2*)eattr;
  float acc = 0.f;
  int e0 = offs[n], e1 = offs[n + 1];
  int i = e0;
  for (; i + 1 < e1; i += 2) {
    int ea_ = csr[i], eb_ = csr[i + 1];
    int sa = src[ea_], sb = src[eb_];
    float2 aa = ea2[ea_], ab = ea2[eb_];
    float va = h[sa * HID + j] + fmaf(aa.x, w0, fmaf(aa.y, w1, b));
    float vb = h[sb * HID + j] + fmaf(ab.x, w0, fmaf(ab.y, w1, b));
    acc += fmaxf(va, 0.f) + fmaxf(vb, 0.f);
  }
  if (i < e1) {
    int ea_ = csr[i];
    int sa = src[ea_];
    float2 aa = ea2[ea_];
    float va = h[sa * HID + j] + fmaf(aa.x, w0, fmaf(aa.y, w1, b));
    acc += fmaxf(va, 0.f);
  }
  float z = h[n * HID + j] + acc;
  zs[nl][j] = z;
  __syncthreads();
  float a1 = b1[j];
#pragma unroll 16
  for (int k = 0; k < HID; ++k) a1 = fmaf(zs[nl][k], W1[k * HID + j], a1);
  float tv = fmaxf(a1, 0.f);
  ts[nl][j] = tv;
  __syncthreads();
  float a2 = b2[j];
#pragma unroll 16
  for (int k = 0; k < HID; ++k) a2 = fmaf(ts[nl][k], W2[k * HID + j], a2);
  hout[n * HID + j] = fmaxf(a2, 0.f);
}

// ---- K4: fused GINE layer 2 + decode prep (h2, hM=h2@M, split-f16 operands) ----
// A (hM rows): padded-row layout, KSPLIT halves per row = [hi|hi|lo]
// B (h2 rows): fragment-major: half8 unit (ct*6+s)*64 + quad*16 + l16, elem j.
//              (col n, k) -> ct=n/16,l16=n%16,s=k/32,quad=(k%32)/8,j=k%8. K=[hi|lo|hi].
// Block 0 additionally zeroes A pad rows 10000..10111.
__global__ __launch_bounds__(256) void k_gine2_prep(
    const float* __restrict__ h, const float* __restrict__ eattr,
    const int* __restrict__ src, const int* __restrict__ csr, const int* __restrict__ offs,
    const float* __restrict__ We, const float* __restrict__ be,
    const float* __restrict__ W1, const float* __restrict__ b1,
    const float* __restrict__ W2, const float* __restrict__ b2,
    const float* __restrict__ Mw, _Float16* __restrict__ Ap, _Float16* __restrict__ Bf) {
  __shared__ float zs[4][HID];
  __shared__ float ts[4][HID];
  __shared__ float hs[4][HID];
  if (blockIdx.x == 0) {  // zero A pad rows (rows 10000..10111), 21504 halves
    unsigned int* pad = (unsigned int*)(Ap + (size_t)N_NODES * KSPLIT);
    for (int idx = threadIdx.x; idx < (NPAD - N_NODES) * KSPLIT / 2; idx += 256) pad[idx] = 0u;
  }
  int t = blockIdx.x * blockDim.x + threadIdx.x;
  int n = t >> 6, j = t & 63, nl = threadIdx.x >> 6;
  float w0 = We[j], w1 = We[HID + j], b = be[j];
  const float2* ea2 = (const float2*)eattr;
  float acc = 0.f;
  int e0 = offs[n], e1 = offs[n + 1];
  int i = e0;
  for (; i + 1 < e1; i += 2) {
    int ea_ = csr[i], eb_ = csr[i + 1];
    int sa = src[ea_], sb = src[eb_];
    float2 aa = ea2[ea_], ab = ea2[eb_];
    float va = h[sa * HID + j] + fmaf(aa.x, w0, fmaf(aa.y, w1, b));
    float vb = h[sb * HID + j] + fmaf(ab.x, w0, fmaf(ab.y, w1, b));
    acc += fmaxf(va, 0.f) + fmaxf(vb, 0.f);
  }
  if (i < e1) {
    int ea_ = csr[i];
    int sa = src[ea_];
    float2 aa = ea2[ea_];
    float va = h[sa * HID + j] + fmaf(aa.x, w0, fmaf(aa.y, w1, b));
    acc += fmaxf(va, 0.f);
  }
  float z = h[n * HID + j] + acc;
  zs[nl][j] = z;
  __syncthreads();
  float a1 = b1[j];
#pragma unroll 16
  for (int k = 0; k < HID; ++k) a1 = fmaf(zs[nl][k], W1[k * HID + j], a1);
  float tv = fmaxf(a1, 0.f);
  ts[nl][j] = tv;
  __syncthreads();
  float a2 = b2[j];
#pragma unroll 16
  for (int k = 0; k < HID; ++k) a2 = fmaf(ts[nl][k], W2[k * HID + j], a2);
  hs[nl][j] = a2;  // h2 (no relu)
  {
    _Float16 bhi = (_Float16)a2;
    _Float16 blo = (_Float16)(a2 - (float)bhi);
    int ct = n >> 4, l16 = n & 15;
    int kk[3] = { j, 64 + j, 128 + j };
    _Float16 vv[3] = { bhi, blo, bhi };
#pragma unroll
    for (int q = 0; q < 3; ++q) {
      int k = kk[q];
      int s = k >> 5, quad = (k & 31) >> 3, jj = k & 7;
      Bf[((((ct * 6 + s) * 64) + quad * 16 + l16) << 3) + jj] = vv[q];
    }
  }
  __syncthreads();
  float accm = 0.f;
#pragma unroll 16
  for (int k = 0; k < HID; ++k) accm = fmaf(hs[nl][k], Mw[k * HID + j], accm);
  _Float16 ahi = (_Float16)accm;
  _Float16 alo = (_Float16)(accm - (float)ahi);
  _Float16* arow = Ap + (size_t)n * KSPLIT;
  arow[j] = ahi; arow[64 + j] = ahi; arow[128 + j] = alo;
}

// ------- K5: pass 1 — frozen-ref online sum-exp (f >= runmax-8 invariant) -------
__global__ __launch_bounds__(256) void k_pass1(
    const _Float16* __restrict__ Ap, const _Float16* __restrict__ Bfh,
    float* __restrict__ pm, float* __restrict__ ps) {
  int seg = blockIdx.x & 15;
  int rg = blockIdx.x >> 4;
  int wave = threadIdx.x >> 6, lane = threadIdx.x & 63;
  int quad = lane >> 4, l16 = lane & 15;
  int rowbase = rg * 128 + wave * 32;
  const half8* A = (const half8*)Ap;   // row stride = 24 half8
  const half8* Bf = (const half8*)Bfh; // fragment-major
  half8 af[2][6];
#pragma unroll
  for (int tt = 0; tt < 2; ++tt) {
    int ar = rowbase + tt * 16 + l16;
#pragma unroll
    for (int s = 0; s < 6; ++s) af[tt][s] = A[ar * 24 + s * 4 + quad];
  }
  float f[8], sm[8];
  int ct0 = seg * TPS;
  int ct1 = ct0 + TPS; if (ct1 > NT) ct1 = NT;
  bool first = true;
  for (int ct = ct0; ct < ct1; ++ct) {
    half8 bf[6];
#pragma unroll
    for (int s = 0; s < 6; ++s) bf[s] = Bf[(ct * 6 + s) * 64 + lane];  // coalesced 1KB
    floatx4 acc0 = {0.f, 0.f, 0.f, 0.f}, acc1 = {0.f, 0.f, 0.f, 0.f};
#pragma unroll
    for (int s = 0; s < 6; ++s) {
      acc0 = __builtin_amdgcn_mfma_f32_16x16x32_f16(af[0][s], bf[s], acc0, 0, 0, 0);
      acc1 = __builtin_amdgcn_mfma_f32_16x16x32_f16(af[1][s], bf[s], acc1, 0, 0, 0);
    }
    float d[8];
#pragma unroll
    for (int i = 0; i < 4; ++i) { d[i] = acc0[i]; d[4 + i] = acc1[i]; }
    if (first) {
      first = false;
#pragma unroll
      for (int i = 0; i < 8; ++i) { f[i] = d[i]; sm[i] = 1.f; }
    } else {
      bool resc = false;
#pragma unroll
      for (int i = 0; i < 8; ++i) resc |= (d[i] > f[i] + 8.f);
      if (__any((int)resc)) {
#pragma unroll
        for (int i = 0; i < 8; ++i) {
          float nf = fmaxf(f[i], d[i]);
          sm[i] = sm[i] * __expf(f[i] - nf) + __expf(d[i] - nf);
          f[i] = nf;
        }
      } else {
#pragma unroll
        for (int i = 0; i < 8; ++i) sm[i] += __expf(d[i] - f[i]);
      }
    }
  }
  // combine (f, sm) across the 16 l16 lanes (cols mod 16)
#pragma unroll
  for (int off = 1; off < 16; off <<= 1) {
#pragma unroll
    for (int i = 0; i < 8; ++i) {
      float fo = __shfl_xor(f[i], off);
      float so = __shfl_xor(sm[i], off);
      float nf = fmaxf(f[i], fo);
      sm[i] = sm[i] * __expf(f[i] - nf) + so * __expf(fo - nf);
      f[i] = nf;
    }
  }
  if (l16 == 0) {
#pragma unroll
    for (int i = 0; i < 8; ++i) {
      int row = rowbase + (i >> 2) * 16 + quad * 4 + (i & 3);
      if (row < N_NODES) {
        pm[seg * N_NODES + row] = f[i];
        ps[seg * N_NODES + row] = sm[i];
      }
    }
  }
}

// ------ K6: pass 2 — fused stat-combine + recompute logits + write softmax ------
__global__ __launch_bounds__(256) void k_pass2(
    const _Float16* __restrict__ Ap, const _Float16* __restrict__ Bfh,
    const float* __restrict__ pm, const float* __restrict__ ps, float* __restrict__ out) {
  __shared__ float Ms[128], Is[128];
  int cs = blockIdx.x % CSEG;
  int rg = blockIdx.x / CSEG;
  // combine per-segment stats for this block's 128 rows
  for (int r = threadIdx.x; r < 128; r += 256) {
    int row = rg * 128 + r;
    if (row < N_NODES) {
      float M = -3.0e38f;
#pragma unroll
      for (int s = 0; s < NSEG; ++s) M = fmaxf(M, pm[s * N_NODES + row]);
      float S = 0.f;
#pragma unroll
      for (int s = 0; s < NSEG; ++s) S += ps[s * N_NODES + row] * __expf(pm[s * N_NODES + row] - M);
      Ms[r] = M; Is[r] = 1.f / S;
    } else { Ms[r] = 0.f; Is[r] = 0.f; }
  }
  int wave = threadIdx.x >> 6, lane = threadIdx.x & 63;
  int quad = lane >> 4, l16 = lane & 15;
  int rowbase = rg * 128 + wave * 32;
  const half8* A = (const half8*)Ap;
  const half8* Bf = (const half8*)Bfh;
  half8 af[2][6];
#pragma unroll
  for (int tt = 0; tt < 2; ++tt) {
    int ar = rowbase + tt * 16 + l16;
#pragma unroll
    for (int s = 0; s < 6; ++s) af[tt][s] = A[ar * 24 + s * 4 + quad];
  }
  __syncthreads();
  float Mv[8], Iv[8];
  int rowv[8];
#pragma unroll
  for (int i = 0; i < 8; ++i) {
    int rl = wave * 32 + (i >> 2) * 16 + quad * 4 + (i & 3);
    rowv[i] = rg * 128 + rl;
    Mv[i] = Ms[rl];
    Iv[i] = Is[rl];
  }
  for (int ct = cs * CSEG; ct < cs * CSEG + CSEG; ++ct) {
    half8 bf[6];
#pragma unroll
    for (int s = 0; s < 6; ++s) bf[s] = Bf[(ct * 6 + s) * 64 + lane];  // coalesced 1KB
    floatx4 acc0 = {0.f, 0.f, 0.f, 0.f}, acc1 = {0.f, 0.f, 0.f, 0.f};
#pragma unroll
    for (int s = 0; s < 6; ++s) {
      acc0 = __builtin_amdgcn_mfma_f32_16x16x32_f16(af[0][s], bf[s], acc0, 0, 0, 0);
      acc1 = __builtin_amdgcn_mfma_f32_16x16x32_f16(af[1][s], bf[s], acc1, 0, 0, 0);
    }
    float d[8];
#pragma unroll
    for (int i = 0; i < 4; ++i) { d[i] = acc0[i]; d[4 + i] = acc1[i]; }
    int col = ct * 16 + l16;
#pragma unroll
    for (int i = 0; i < 8; ++i) {
      if (rowv[i] < N_NODES) {
        float v = __expf(d[i] - Mv[i]) * Iv[i];
        __builtin_nontemporal_store(v, &out[(size_t)rowv[i] * N_NODES + col]);
      }
    }
  }
}

extern "C" void kernel_launch(void* const* d_in, const int* in_sizes, int n_in,
                              void* d_out, int out_size, void* d_ws, size_t ws_size,
                              hipStream_t stream) {
  const float* x     = (const float*)d_in[0];
  const float* eattr = (const float*)d_in[1];
  const int*   eidx  = (const int*)d_in[2];
  const float* Win   = (const float*)d_in[3];
  const float* bin   = (const float*)d_in[4];
  const float* We    = (const float*)d_in[5];
  const float* be    = (const float*)d_in[6];
  const float* W1    = (const float*)d_in[7];
  const float* b1    = (const float*)d_in[8];
  const float* W2    = (const float*)d_in[9];
  const float* b2    = (const float*)d_in[10];
  const float* Mw    = (const float*)d_in[11];
  float* out = (float*)d_out;
  const int* src = eidx;
  const int* dst = eidx + N_EDGES;

  char* w = (char*)d_ws;
  auto alloc = [&](size_t bytes) { char* p = w; w += (bytes + 255) & ~(size_t)255; return p; };
  float*    h0   = (float*)alloc((size_t)N_NODES * HID * 4);
  float*    h1   = (float*)alloc((size_t)N_NODES * HID * 4);
  _Float16* Ap   = (_Float16*)alloc((size_t)NPAD * KSPLIT * 2);
  _Float16* Bf   = (_Float16*)alloc((size_t)NT * 6 * 64 * 8 * 2);  // 3.84 MB fragment-major
  int*      csr  = (int*)alloc((size_t)N_EDGES * 4);
  int*      cnt  = (int*)alloc((size_t)(N_NODES + 1) * 4);
  int*      offs = (int*)alloc((size_t)(N_NODES + 1) * 4);
  int*      cur  = (int*)alloc((size_t)(N_NODES + 1) * 4);
  float*    pm   = (float*)alloc((size_t)NSEG * N_NODES * 4);
  float*    ps   = (float*)alloc((size_t)NSEG * N_NODES * 4);

  hipMemsetAsync(cnt, 0, (N_NODES + 1) * 4, stream);

  k_embed_hist<<<(N_NODES * HID) / 256, 256, 0, stream>>>(x, Win, bin, h0, dst, cnt);
  k_scan<<<1, 1024, 0, stream>>>(cnt, offs, cur);
  k_scatter<<<N_EDGES / 256, 256, 0, stream>>>(dst, cur, csr);

  k_gine1<<<(N_NODES * HID) / 256, 256, 0, stream>>>(
      h0, eattr, src, csr, offs, We, be, W1, b1, W2, b2, h1);
  k_gine2_prep<<<(N_NODES * HID) / 256, 256, 0, stream>>>(
      h1, eattr, src, csr, offs, We, be, W1, b1, W2, b2, Mw, Ap, Bf);

  k_pass1<<<79 * NSEG, 256, 0, stream>>>(Ap, Bf, pm, ps);
  k_pass2<<<79 * CSEG, 256, 0, stream>>>(Ap, Bf, pm, ps, out);
}